// Round 1
// baseline (2343.037 us; speedup 1.0000x reference)
//
#include <hip/hip_runtime.h>
#include <hip/hip_bf16.h>
#include <math.h>

#define BB 256
#define TT 128
#define DD 1024
#define CFF 128
#define HH 128
#define G4 512
#define NK 9

__device__ __forceinline__ float bf_lo(unsigned u){ union{unsigned u; float f;} v; v.u = u << 16; return v.f; }
__device__ __forceinline__ float bf_hi(unsigned u){ union{unsigned u; float f;} v; v.u = u & 0xffff0000u; return v.f; }
__device__ __forceinline__ unsigned f2bf(float x){
    union{float f; unsigned u;} v; v.f = x;
    unsigned r = v.u + 0x7fffu + ((v.u >> 16) & 1u);
    return r >> 16;
}
__device__ __forceinline__ float fsigmoid(float x){ return 1.0f/(1.0f + __expf(-x)); }
__device__ __forceinline__ float ftanh(float x){
    float a = fabsf(x);
    float e = __expf(-2.0f*a);
    float r = (1.0f - e)/(1.0f + e);
    return x >= 0.f ? r : -r;
}
__device__ __forceinline__ float gelu_exact(float x){
    return 0.5f*x*(1.0f + erff(x*0.70710678118654752440f));
}

// ---------------- conv5: (B,T,D) x (CF,D,5) -> y1 (B,T,CF) ----------------
__global__ __launch_bounds__(256) void conv5_kernel(
    const float* __restrict__ x, const float* __restrict__ w,
    const float* __restrict__ bias, float* __restrict__ y)
{
    __shared__ __align__(16) float xs[36][64];
    int blk = blockIdx.x;
    int b = blk >> 2;
    int t0 = (blk & 3) << 5;
    int f = threadIdx.x & 127;
    int th = threadIdx.x >> 7;
    float acc[16];
#pragma unroll
    for (int i = 0; i < 16; ++i) acc[i] = 0.f;

    for (int d0 = 0; d0 < DD; d0 += 64) {
        __syncthreads();
        for (int i = threadIdx.x; i < 576; i += 256) {
            int r = i >> 4;
            int c4 = (i & 15) << 2;
            int t = t0 - 2 + r;
            float4 v = make_float4(0.f, 0.f, 0.f, 0.f);
            if (t >= 0 && t < TT)
                v = *reinterpret_cast<const float4*>(&x[((size_t)b*TT + t)*DD + d0 + c4]);
            *reinterpret_cast<float4*>(&xs[r][c4]) = v;
        }
        __syncthreads();
        const float* wp = &w[((size_t)f*DD + d0)*5];
        int rbase = th << 4;
        for (int dd = 0; dd < 64; ++dd) {
            float w0 = wp[0], w1 = wp[1], w2 = wp[2], w3 = wp[3], w4 = wp[4];
            wp += 5;
            float xv[20];
#pragma unroll
            for (int r = 0; r < 20; ++r) xv[r] = xs[rbase + r][dd];
#pragma unroll
            for (int t = 0; t < 16; ++t)
                acc[t] += xv[t]*w0 + xv[t+1]*w1 + xv[t+2]*w2 + xv[t+3]*w3 + xv[t+4]*w4;
        }
    }
    float bv = bias[f];
#pragma unroll
    for (int t = 0; t < 16; ++t) {
        int tt = t0 + (th << 4) + t;
        y[((size_t)b*TT + tt)*CFF + f] = acc[t] + bv;
    }
}

// ---------------- conv7/conv9 over LSTM output (B,T,256) ----------------
template<int KS>
__global__ __launch_bounds__(256) void convk_kernel(
    const float* __restrict__ in,   // hfb (B,T,256), in[b,ci,t] = hfb[(b*T+t)*256+ci]
    const float* __restrict__ w,    // (128,256,KS)
    const float* __restrict__ bias,
    float* __restrict__ out,        // c79 (B,T,256), channel offset co_off
    int co_off)
{
    constexpr int PAD = KS / 2;
    constexpr int ROWS = 32 + KS - 1;
    __shared__ __align__(16) float xs[ROWS][64];
    int blk = blockIdx.x;
    int b = blk >> 2;
    int t0 = (blk & 3) << 5;
    int co = threadIdx.x & 127;
    int th = threadIdx.x >> 7;
    float acc[16];
#pragma unroll
    for (int i = 0; i < 16; ++i) acc[i] = 0.f;

    for (int d0 = 0; d0 < 256; d0 += 64) {
        __syncthreads();
        for (int i = threadIdx.x; i < ROWS*16; i += 256) {
            int r = i >> 4;
            int c4 = (i & 15) << 2;
            int t = t0 - PAD + r;
            float4 v = make_float4(0.f, 0.f, 0.f, 0.f);
            if (t >= 0 && t < TT)
                v = *reinterpret_cast<const float4*>(&in[((size_t)b*TT + t)*256 + d0 + c4]);
            *reinterpret_cast<float4*>(&xs[r][c4]) = v;
        }
        __syncthreads();
        int rbase = th << 4;
        for (int dd = 0; dd < 64; ++dd) {
            const float* wp = &w[((size_t)co*256 + d0 + dd)*KS];
            float wk[KS];
#pragma unroll
            for (int k = 0; k < KS; ++k) wk[k] = wp[k];
            float xv[16 + KS - 1];
#pragma unroll
            for (int r = 0; r < 16 + KS - 1; ++r) xv[r] = xs[rbase + r][dd];
#pragma unroll
            for (int t = 0; t < 16; ++t) {
                float s = acc[t];
#pragma unroll
                for (int k = 0; k < KS; ++k) s += xv[t + k]*wk[k];
                acc[t] = s;
            }
        }
    }
    float bv = bias[co];
#pragma unroll
    for (int t = 0; t < 16; ++t) {
        int tt = t0 + (th << 4) + t;
        out[((size_t)b*TT + tt)*256 + co_off + co] = acc[t] + bv;
    }
}

// ---------------- BN stats (rows = B*T, channels C; C in {128,256}) ----------------
__global__ __launch_bounds__(256) void bn_stats_kernel(
    const float* __restrict__ y, int C, int rows_per_blk,
    float* __restrict__ sum, float* __restrict__ sqsum)
{
    int tpc = 256 / C;
    int c = threadIdx.x & (C - 1);
    int sub = threadIdx.x / C;
    size_t r0 = (size_t)blockIdx.x * rows_per_blk;
    float s = 0.f, s2 = 0.f;
    for (int r = sub; r < rows_per_blk; r += tpc) {
        float v = y[(r0 + r)*C + c];
        s += v; s2 += v*v;
    }
    __shared__ float ls[256], ls2[256];
    ls[threadIdx.x] = s; ls2[threadIdx.x] = s2;
    __syncthreads();
    if (sub == 0) {
        for (int k = 1; k < tpc; ++k) { s += ls[c + k*C]; s2 += ls2[c + k*C]; }
        atomicAdd(&sum[c], s);
        atomicAdd(&sqsum[c], s2);
    }
}

__global__ __launch_bounds__(256) void bn_gelu_kernel(
    float* __restrict__ y, int Cmask, const float* __restrict__ sum,
    const float* __restrict__ sqsum, const float* __restrict__ g,
    const float* __restrict__ beta, float inv_n)
{
    size_t i = (size_t)blockIdx.x*256 + threadIdx.x;
    int c = (int)(i & (size_t)Cmask);
    float m = sum[c] * inv_n;
    float var = fmaxf(sqsum[c]*inv_n - m*m, 0.f);
    float xv = (y[i] - m) * rsqrtf(var + 1e-5f) * g[c] + beta[c];
    y[i] = gelu_exact(xv);
}

// ---------------- xg = xl @ Wih^T + bih + bhh, stored bf16 ----------------
__global__ __launch_bounds__(256) void xg_gemm_kernel(
    const float* __restrict__ xl,
    const float* __restrict__ Wf, const float* __restrict__ bif, const float* __restrict__ bhf,
    const float* __restrict__ Wb, const float* __restrict__ bib, const float* __restrict__ bhb,
    __hip_bfloat16* __restrict__ xgf, __hip_bfloat16* __restrict__ xgb)
{
    __shared__ __align__(16) float xs[32][CFF];
    int r0 = blockIdx.x << 5;
    int grp = blockIdx.y;
    int dir = grp >> 2;
    int g0 = (grp & 3) << 7;
    const float* W  = dir ? Wb : Wf;
    const float* bi = dir ? bib : bif;
    const float* bh = dir ? bhb : bhf;
    __hip_bfloat16* out = dir ? xgb : xgf;

    for (int i = threadIdx.x; i < 1024; i += 256) {
        int r = i >> 5;
        int c4 = (i & 31) << 2;
        *reinterpret_cast<float4*>(&xs[r][c4]) =
            *reinterpret_cast<const float4*>(&xl[((size_t)(r0 + r))*CFF + c4]);
    }
    __syncthreads();
    int j = threadIdx.x & 127;
    int half = threadIdx.x >> 7;
    int gidx = g0 + j;
    const float* wrow = &W[(size_t)gidx * CFF];
    float acc[16];
#pragma unroll
    for (int i = 0; i < 16; ++i) acc[i] = 0.f;
    for (int k = 0; k < CFF; k += 4) {
        float4 wv = *reinterpret_cast<const float4*>(&wrow[k]);
#pragma unroll
        for (int t = 0; t < 16; ++t) {
            int r = (half << 4) + t;
            float4 xv = *reinterpret_cast<const float4*>(&xs[r][k]);
            acc[t] += xv.x*wv.x + xv.y*wv.y + xv.z*wv.z + xv.w*wv.w;
        }
    }
    float bsum = bi[gidx] + bh[gidx];
#pragma unroll
    for (int t = 0; t < 16; ++t) {
        int r = (half << 4) + t;
        out[((size_t)(r0 + r))*G4 + gidx] = __float2bfloat16(acc[t] + bsum);
    }
}

// ---------------- persistent bi-LSTM: 2 batches per block ----------------
__global__ __launch_bounds__(512) void lstm_kernel(
    const __hip_bfloat16* __restrict__ xgf, const __hip_bfloat16* __restrict__ xgb,
    const float* __restrict__ Whhf, const float* __restrict__ Whhb,
    float* __restrict__ hfb)
{
    int dir = blockIdx.x >> 7;
    int bp  = blockIdx.x & 127;
    int b0  = bp << 1;
    const __hip_bfloat16* xg = dir ? xgb : xgf;
    const float* Whh = dir ? Whhb : Whhf;

    int tid = threadIdx.x;           // row of Whh: [i(0:128) f g o]
    int gate = tid >> 7;
    unsigned wrow[64];
    {
        const float* wr = &Whh[(size_t)tid * HH];
#pragma unroll
        for (int k = 0; k < 64; ++k) {
            unsigned lo = f2bf(wr[2*k]);
            unsigned hi = f2bf(wr[2*k + 1]);
            wrow[k] = lo | (hi << 16);
        }
    }
    __shared__ __align__(16) float h_lds[2][HH];
    __shared__ float act_lds[4][2][HH];
    if (tid < 256) h_lds[tid >> 7][tid & 127] = 0.f;
    float creg = 0.f;
    __syncthreads();

    for (int s = 0; s < TT; ++s) {
        int t = dir ? (TT - 1 - s) : s;
        float acc0 = 0.f, acc1 = 0.f;
#pragma unroll
        for (int k = 0; k < 64; k += 2) {
            float4 h0 = *reinterpret_cast<const float4*>(&h_lds[0][k << 1]);
            float4 h1 = *reinterpret_cast<const float4*>(&h_lds[1][k << 1]);
            unsigned u0 = wrow[k], u1 = wrow[k + 1];
            float w0 = bf_lo(u0), w1 = bf_hi(u0), w2 = bf_lo(u1), w3 = bf_hi(u1);
            acc0 += h0.x*w0 + h0.y*w1 + h0.z*w2 + h0.w*w3;
            acc1 += h1.x*w0 + h1.y*w1 + h1.z*w2 + h1.w*w3;
        }
        float x0 = __bfloat162float(xg[(((size_t)b0    )*TT + t)*G4 + tid]);
        float x1 = __bfloat162float(xg[(((size_t)b0 + 1)*TT + t)*G4 + tid]);
        float p0 = acc0 + x0, p1 = acc1 + x1;
        float a0, a1;
        if (gate == 2) { a0 = ftanh(p0);    a1 = ftanh(p1); }
        else           { a0 = fsigmoid(p0); a1 = fsigmoid(p1); }
        act_lds[gate][0][tid & 127] = a0;
        act_lds[gate][1][tid & 127] = a1;
        __syncthreads();
        if (tid < 256) {
            int ub = tid >> 7, uj = tid & 127;
            float iv = act_lds[0][ub][uj];
            float fv = act_lds[1][ub][uj];
            float gv = act_lds[2][ub][uj];
            float ov = act_lds[3][ub][uj];
            creg = fv*creg + iv*gv;
            float hv = ov * ftanh(creg);
            h_lds[ub][uj] = hv;
            hfb[(((size_t)(b0 + ub))*TT + t)*256 + dir*HH + uj] = hv;
        }
        __syncthreads();
    }
}

// ---------------- logits = feat @ cls_w^T + cls_b ----------------
__global__ __launch_bounds__(256) void logits_kernel(
    const float* __restrict__ feat, const float* __restrict__ cw,
    const float* __restrict__ cb, float* __restrict__ lg)
{
    __shared__ float wls[NK*256];
    for (int i = threadIdx.x; i < NK*256; i += 256) wls[i] = cw[i];
    __syncthreads();
    size_t row = (size_t)blockIdx.x*256 + threadIdx.x;
    const float* fr = &feat[row*256];
    float acc[NK];
#pragma unroll
    for (int k = 0; k < NK; ++k) acc[k] = 0.f;
    for (int c = 0; c < 256; c += 4) {
        float4 v = *reinterpret_cast<const float4*>(&fr[c]);
#pragma unroll
        for (int k = 0; k < NK; ++k)
            acc[k] += v.x*wls[k*256 + c] + v.y*wls[k*256 + c + 1]
                    + v.z*wls[k*256 + c + 2] + v.w*wls[k*256 + c + 3];
    }
#pragma unroll
    for (int k = 0; k < NK; ++k) lg[row*NK + k] = acc[k] + cb[k];
}

// ---------------- weighted CE over all positions ----------------
__global__ __launch_bounds__(256) void ce_kernel(
    const float* __restrict__ lg, const int* __restrict__ labels,
    const float* __restrict__ cw, float* __restrict__ acc2)
{
    size_t i = (size_t)blockIdx.x*256 + threadIdx.x;
    const float* l = &lg[i*NK];
    float mx = -1e30f;
#pragma unroll
    for (int k = 0; k < NK; ++k) mx = fmaxf(mx, l[k]);
    float se = 0.f;
#pragma unroll
    for (int k = 0; k < NK; ++k) se += expf(l[k] - mx);
    float lz = mx + logf(se);
    int y = labels[i];
    bool valid = (y != -100);
    int yi = valid ? y : 0;
    float nll = lz - l[yi];
    float wv = valid ? cw[yi] : 0.f;
    __shared__ float s1[256], s2[256];
    s1[threadIdx.x] = wv*nll;
    s2[threadIdx.x] = wv;
    __syncthreads();
    for (int s = 128; s > 0; s >>= 1) {
        if (threadIdx.x < s) { s1[threadIdx.x] += s1[threadIdx.x + s]; s2[threadIdx.x] += s2[threadIdx.x + s]; }
        __syncthreads();
    }
    if (threadIdx.x == 0) { atomicAdd(&acc2[0], s1[0]); atomicAdd(&acc2[1], s2[0]); }
}

// ---------------- CRF: one wave per sequence ----------------
__global__ __launch_bounds__(64) void crf_kernel(
    const float* __restrict__ lg, const int* __restrict__ att,
    const int* __restrict__ labels, const float* __restrict__ startv,
    const float* __restrict__ trans, const float* __restrict__ endv,
    float* __restrict__ numo, float* __restrict__ logzo)
{
    int b = blockIdx.x;
    int lane = threadIdx.x;
    int lane_c = (lane < NK) ? lane : 0;
    const float* em = &lg[(size_t)b*TT*NK];
    float tr[NK];
#pragma unroll
    for (int i = 0; i < NK; ++i) tr[i] = trans[i*NK + lane_c];
    float score = startv[lane_c] + em[lane_c];

    for (int t = 1; t < TT; ++t) {
        int lt = labels[b*TT + t];
        bool m = (att[b*TT + t] != 0) && (lt != -100);
        float vals[NK];
#pragma unroll
        for (int i = 0; i < NK; ++i)
            vals[i] = __shfl(score, i, 64) + tr[i];
        if (m) {
            float mx = vals[0];
#pragma unroll
            for (int i = 1; i < NK; ++i) mx = fmaxf(mx, vals[i]);
            float sm = 0.f;
#pragma unroll
            for (int i = 0; i < NK; ++i) sm += expf(vals[i] - mx);
            score = mx + logf(sm) + em[t*NK + lane_c];
        }
    }
    float fin = (lane < NK) ? (score + endv[lane_c]) : -1e30f;
    float mx = -1e30f;
#pragma unroll
    for (int i = 0; i < NK; ++i) mx = fmaxf(mx, __shfl(fin, i, 64));
    float sm = 0.f;
#pragma unroll
    for (int i = 0; i < NK; ++i) sm += expf(__shfl(fin, i, 64) - mx);
    if (lane == 0) logzo[b] = mx + logf(sm);

    if (lane == 0) {
        int l0 = labels[b*TT];
        int tag0 = (l0 == -100) ? 0 : l0;
        bool m0 = (att[b*TT] != 0) && (l0 != -100);
        float num = startv[tag0] + em[tag0];
        int prev = tag0;
        int cnt = m0 ? 1 : 0;
        for (int t = 1; t < TT; ++t) {
            int lt = labels[b*TT + t];
            bool m = (att[b*TT + t] != 0) && (lt != -100);
            int tag = (lt == -100) ? 0 : lt;
            if (m) { num += trans[prev*NK + tag] + em[t*NK + tag]; cnt++; }
            prev = tag;
        }
        int le = cnt - 1; if (le < 0) le = 0; if (le >= TT) le = TT - 1;
        int ll = labels[b*TT + le];
        int ltag = (ll == -100) ? 0 : ll;
        num += endv[ltag];
        numo[b] = num;
    }
}

__global__ __launch_bounds__(256) void finalize_kernel(
    const float* __restrict__ numo, const float* __restrict__ logzo,
    const float* __restrict__ acc2, float* __restrict__ out)
{
    __shared__ float red[256];
    int tid = threadIdx.x;
    red[tid] = numo[tid] - logzo[tid];
    __syncthreads();
    for (int s = 128; s > 0; s >>= 1) {
        if (tid < s) red[tid] += red[tid + s];
        __syncthreads();
    }
    if (tid == 0) {
        float crf = -(red[0] / (float)BB);
        float ce = acc2[0] / acc2[1];
        out[0] = 0.8f*crf + 0.2f*ce;
    }
}

extern "C" void kernel_launch(void* const* d_in, const int* in_sizes, int n_in,
                              void* d_out, int out_size, void* d_ws, size_t ws_size,
                              hipStream_t stream)
{
    const float* emb   = (const float*)d_in[0];
    const int*   att   = (const int*)  d_in[1];
    const int*   lab   = (const int*)  d_in[2];
    const float* c5w   = (const float*)d_in[3];
    const float* c5b   = (const float*)d_in[4];
    const float* bn1g  = (const float*)d_in[5];
    const float* bn1b  = (const float*)d_in[6];
    const float* Wihf  = (const float*)d_in[7];
    const float* Whhf  = (const float*)d_in[8];
    const float* bihf  = (const float*)d_in[9];
    const float* bhhf  = (const float*)d_in[10];
    const float* Wihb  = (const float*)d_in[11];
    const float* Whhb  = (const float*)d_in[12];
    const float* bihb  = (const float*)d_in[13];
    const float* bhhb  = (const float*)d_in[14];
    const float* c7w   = (const float*)d_in[15];
    const float* c7b   = (const float*)d_in[16];
    const float* c9w   = (const float*)d_in[17];
    const float* c9b   = (const float*)d_in[18];
    const float* bn2g  = (const float*)d_in[19];
    const float* bn2b  = (const float*)d_in[20];
    const float* clsw  = (const float*)d_in[21];
    const float* clsb  = (const float*)d_in[22];
    const float* cstart= (const float*)d_in[23];
    const float* ctrans= (const float*)d_in[24];
    const float* cend  = (const float*)d_in[25];
    const float* cwts  = (const float*)d_in[26];
    (void)in_sizes; (void)n_in; (void)out_size; (void)ws_size;

    char* wsb = (char*)d_ws;
    size_t off = 0;
    float* y1 = (float*)(wsb + off);                       off += (size_t)4194304*4;
    __hip_bfloat16* xgf = (__hip_bfloat16*)(wsb + off);
    float* c79 = (float*)(wsb + off);                      // aliases xg (dead by then)
    off += (size_t)16777216*2;
    __hip_bfloat16* xgb = (__hip_bfloat16*)(wsb + off);    off += (size_t)16777216*2;
    float* hfb = (float*)(wsb + off);                      off += (size_t)8388608*4;
    float* lg  = (float*)(wsb + off);                      off += (size_t)294912*4;
    float* stats = (float*)(wsb + off);
    float* bn1s = stats;
    float* bn1q = stats + 128;
    float* bn2s = stats + 256;
    float* bn2q = stats + 512;
    float* acc2 = stats + 768;   // [0]=sum w*nll, [1]=sum w
    float* numo = stats + 770;
    float* logzo = numo + 256;

    hipMemsetAsync(stats, 0, 770*sizeof(float), stream);

    conv5_kernel<<<BB*4, 256, 0, stream>>>(emb, c5w, c5b, y1);
    bn_stats_kernel<<<256, 256, 0, stream>>>(y1, 128, 128, bn1s, bn1q);
    bn_gelu_kernel<<<16384, 256, 0, stream>>>(y1, 127, bn1s, bn1q, bn1g, bn1b, 1.0f/32768.f);
    {
        dim3 g(1024, 8);
        xg_gemm_kernel<<<g, 256, 0, stream>>>(y1, Wihf, bihf, bhhf, Wihb, bihb, bhhb, xgf, xgb);
    }
    lstm_kernel<<<256, 512, 0, stream>>>(xgf, xgb, Whhf, Whhb, hfb);
    convk_kernel<7><<<BB*4, 256, 0, stream>>>(hfb, c7w, c7b, c79, 0);
    convk_kernel<9><<<BB*4, 256, 0, stream>>>(hfb, c9w, c9b, c79, 128);
    bn_stats_kernel<<<256, 256, 0, stream>>>(c79, 256, 128, bn2s, bn2q);
    bn_gelu_kernel<<<32768, 256, 0, stream>>>(c79, 255, bn2s, bn2q, bn2g, bn2b, 1.0f/32768.f);
    logits_kernel<<<128, 256, 0, stream>>>(c79, clsw, clsb, lg);
    ce_kernel<<<128, 256, 0, stream>>>(lg, lab, cwts, acc2);
    crf_kernel<<<BB, 64, 0, stream>>>(lg, att, lab, cstart, ctrans, cend, numo, logzo);
    finalize_kernel<<<1, 256, 0, stream>>>(numo, logzo, acc2, (float*)d_out);
}

// Round 2
// 850.243 us; speedup vs baseline: 2.7557x; 2.7557x over previous
//
#include <hip/hip_runtime.h>
#include <hip/hip_bf16.h>
#include <math.h>

#define BB 256
#define TT 128
#define DD 1024
#define CFF 128
#define HH 128
#define G4 512
#define NK 9

typedef __attribute__((ext_vector_type(8))) short bf16x8;
typedef __attribute__((ext_vector_type(4))) float f32x4;

__device__ __forceinline__ float bf_lo(unsigned u){ union{unsigned u; float f;} v; v.u = u << 16; return v.f; }
__device__ __forceinline__ float bf_hi(unsigned u){ union{unsigned u; float f;} v; v.u = u & 0xffff0000u; return v.f; }
__device__ __forceinline__ float bfu2f(ushort u){ union{unsigned u; float f;} v; v.u = ((unsigned)u) << 16; return v.f; }
__device__ __forceinline__ unsigned f2bf(float x){
    union{float f; unsigned u;} v; v.f = x;
    unsigned r = v.u + 0x7fffu + ((v.u >> 16) & 1u);
    return r >> 16;
}
__device__ __forceinline__ float fsigmoid(float x){ return 1.0f/(1.0f + __expf(-x)); }
__device__ __forceinline__ float ftanh(float x){
    float a = fabsf(x);
    float e = __expf(-2.0f*a);
    float r = (1.0f - e)/(1.0f + e);
    return x >= 0.f ? r : -r;
}
__device__ __forceinline__ float gelu_exact(float x){
    return 0.5f*x*(1.0f + erff(x*0.70710678118654752440f));
}

// ---------------- weight prep: w[f][d][k] (f32) -> Wk[(k*128+f)*CIN+d] (bf16) ----------------
__global__ __launch_bounds__(256) void prep_convw_kernel(
    const float* __restrict__ w, ushort* __restrict__ Wk, int CIN, int KS, int total)
{
    int i = blockIdx.x*256 + threadIdx.x;
    if (i >= total) return;
    int k = i % KS;
    int d = (i / KS) % CIN;
    int f = i / (KS * CIN);
    Wk[((size_t)(k*128 + f))*CIN + d] = (ushort)f2bf(w[i]);
}

// ---------------- xg weight/bias prep ----------------
__global__ __launch_bounds__(256) void prep_xg_kernel(
    const float* __restrict__ Wf, const float* __restrict__ Wb,
    const float* __restrict__ bif, const float* __restrict__ bhf,
    const float* __restrict__ bib, const float* __restrict__ bhb,
    ushort* __restrict__ Wxg, float* __restrict__ bias_xg)
{
    int i = blockIdx.x*256 + threadIdx.x;
    if (i < 65536) Wxg[i] = (ushort)f2bf(Wf[i]);
    else if (i < 131072) Wxg[i] = (ushort)f2bf(Wb[i - 65536]);
    else {
        int j = i - 131072;
        if (j < 512) bias_xg[j] = bif[j] + bhf[j];
        else if (j < 1024) bias_xg[j] = bib[j-512] + bhb[j-512];
    }
}

// ---------------- implicit-GEMM conv via MFMA ----------------
// out[row][f] = bias[f] + sum_{k,d} in[row + k - PAD][d] * Wk[(k*128+f)*CIN + d]
// block: 128 rows x 128 cols; 4 waves of 64x64; BK=32 per step.
template<int CIN, int KS, bool IN_F32, bool OUT_BF16>
__global__ __launch_bounds__(256) void conv_mfma_kernel(
    const void* __restrict__ in_v,
    const ushort* __restrict__ Wk_g,
    const float* __restrict__ bias_g,
    void* __restrict__ out_v,
    int OS, size_t out_dir_stride)
{
    constexpr int PAD = KS / 2;
    constexpr int ROWS = 128 + 2 * PAD;
    constexpr int AST = 40;              // padded row stride (bf16): 80B -> conflict-free-ish
    constexpr int NSTEP = CIN / 32;
    __shared__ ushort A_lds[ROWS * AST];
    __shared__ ushort B_lds[KS * 128 * AST];

    const int tid = threadIdx.x;
    const size_t row0 = (size_t)blockIdx.x * 128;
    const int by = blockIdx.y;
    const ushort* __restrict__ Wk = Wk_g + (size_t)by * 16384;
    const float* __restrict__ bias = bias_g + (size_t)by * 128;

    f32x4 acc[4][4];
#pragma unroll
    for (int m = 0; m < 4; ++m)
#pragma unroll
        for (int n = 0; n < 4; ++n)
            acc[m][n] = (f32x4){0.f, 0.f, 0.f, 0.f};

    if (PAD > 0) {
        for (int i = tid; i < PAD * AST; i += 256) {
            A_lds[i] = 0;
            A_lds[(PAD + 128) * AST + i] = 0;
        }
    }

    const int lane = tid & 63;
    const int wave = tid >> 6;
    const int lr = lane & 15;
    const int lk = lane >> 4;
    const int wm = wave >> 1;
    const int wn = wave & 1;
    const int abase = (wm * 64 + lr) * AST + lk * 8;

    for (int s = 0; s < NSTEP; ++s) {
        const int d0 = s * 32;
        __syncthreads();
        // ---- stage A (128 interior rows x 32 channels) ----
        if constexpr (IN_F32) {
            const float* __restrict__ inp = (const float*)in_v;
            for (int i = tid; i < 1024; i += 256) {
                int r = i >> 3, c = i & 7;
                float4 v = *reinterpret_cast<const float4*>(&inp[(row0 + r) * CIN + d0 + c * 4]);
                ushort4 h;
                h.x = (ushort)f2bf(v.x); h.y = (ushort)f2bf(v.y);
                h.z = (ushort)f2bf(v.z); h.w = (ushort)f2bf(v.w);
                *reinterpret_cast<ushort4*>(&A_lds[(PAD + r) * AST + c * 4]) = h;
            }
        } else {
            const ushort* __restrict__ inp = (const ushort*)in_v;
            for (int i = tid; i < 512; i += 256) {
                int r = i >> 2, c = i & 3;
                int4 v = *reinterpret_cast<const int4*>(&inp[(row0 + r) * CIN + d0 + c * 8]);
                *reinterpret_cast<int4*>(&A_lds[(PAD + r) * AST + c * 8]) = v;
            }
        }
        // ---- stage B (KS tiles of 128 rows x 32) ----
        for (int i = tid; i < KS * 128 * 4; i += 256) {
            int k = i >> 9;
            int rem = i & 511;
            int f = rem >> 2, c = rem & 3;
            int4 v = *reinterpret_cast<const int4*>(&Wk[((size_t)((k << 7) + f)) * CIN + d0 + c * 8]);
            *reinterpret_cast<int4*>(&B_lds[((k << 7) + f) * AST + c * 8]) = v;
        }
        __syncthreads();
        // ---- compute: for each shift k, 4x4 frags of 16x16x32 ----
#pragma unroll
        for (int k = 0; k < KS; ++k) {
            bf16x8 af[4], bfr[4];
#pragma unroll
            for (int m = 0; m < 4; ++m)
                af[m] = *reinterpret_cast<const bf16x8*>(&A_lds[abase + (m * 16 + k) * AST]);
#pragma unroll
            for (int n = 0; n < 4; ++n)
                bfr[n] = *reinterpret_cast<const bf16x8*>(&B_lds[((k << 7) + wn * 64 + n * 16 + lr) * AST + lk * 8]);
#pragma unroll
            for (int m = 0; m < 4; ++m)
#pragma unroll
                for (int n = 0; n < 4; ++n)
                    acc[m][n] = __builtin_amdgcn_mfma_f32_16x16x32_bf16(af[m], bfr[n], acc[m][n], 0, 0, 0);
        }
    }

    // ---- epilogue: C layout col=lane&15, row=(lane>>4)*4+reg ----
    float bv[4];
#pragma unroll
    for (int n = 0; n < 4; ++n) bv[n] = bias[wn * 64 + n * 16 + lr];
    size_t out_off = (size_t)(by >> 2) * out_dir_stride + (size_t)(by & 3) * 128;
#pragma unroll
    for (int m = 0; m < 4; ++m) {
#pragma unroll
        for (int n = 0; n < 4; ++n) {
            int f = wn * 64 + n * 16 + lr;
#pragma unroll
            for (int j = 0; j < 4; ++j) {
                int t = wm * 64 + m * 16 + lk * 4 + j;
                float val = acc[m][n][j] + bv[n];
                if constexpr (OUT_BF16)
                    ((ushort*)out_v)[out_off + (row0 + t) * (size_t)OS + f] = (ushort)f2bf(val);
                else
                    ((float*)out_v)[out_off + (row0 + t) * (size_t)OS + f] = val;
            }
        }
    }
}

// ---------------- BN stats (rows = B*T, channels C; C in {128,256}) ----------------
__global__ __launch_bounds__(256) void bn_stats_kernel(
    const float* __restrict__ y, int C, int rows_per_blk,
    float* __restrict__ sum, float* __restrict__ sqsum)
{
    int tpc = 256 / C;
    int c = threadIdx.x & (C - 1);
    int sub = threadIdx.x / C;
    size_t r0 = (size_t)blockIdx.x * rows_per_blk;
    float s = 0.f, s2 = 0.f;
    for (int r = sub; r < rows_per_blk; r += tpc) {
        float v = y[(r0 + r)*C + c];
        s += v; s2 += v*v;
    }
    __shared__ float ls[256], ls2[256];
    ls[threadIdx.x] = s; ls2[threadIdx.x] = s2;
    __syncthreads();
    if (sub == 0) {
        for (int k = 1; k < tpc; ++k) { s += ls[c + k*C]; s2 += ls2[c + k*C]; }
        atomicAdd(&sum[c], s);
        atomicAdd(&sqsum[c], s2);
    }
}

__global__ __launch_bounds__(256) void bn_gelu_kernel(
    float* __restrict__ y, int Cmask, const float* __restrict__ sum,
    const float* __restrict__ sqsum, const float* __restrict__ g,
    const float* __restrict__ beta, float inv_n)
{
    size_t i = (size_t)blockIdx.x*256 + threadIdx.x;
    int c = (int)(i & (size_t)Cmask);
    float m = sum[c] * inv_n;
    float var = fmaxf(sqsum[c]*inv_n - m*m, 0.f);
    float xv = (y[i] - m) * rsqrtf(var + 1e-5f) * g[c] + beta[c];
    y[i] = gelu_exact(xv);
}

// ---------------- persistent bi-LSTM: 2 batches per block ----------------
__global__ __launch_bounds__(512) void lstm_kernel(
    const ushort* __restrict__ xgf, const ushort* __restrict__ xgb,
    const float* __restrict__ Whhf, const float* __restrict__ Whhb,
    ushort* __restrict__ hfb)
{
    int dir = blockIdx.x >> 7;
    int bp  = blockIdx.x & 127;
    int b0  = bp << 1;
    const ushort* xg = dir ? xgb : xgf;
    const float* Whh = dir ? Whhb : Whhf;

    int tid = threadIdx.x;           // row of Whh: [i(0:128) f g o]
    int gate = tid >> 7;
    unsigned wrow[64];
    {
        const float* wr = &Whh[(size_t)tid * HH];
#pragma unroll
        for (int k = 0; k < 64; ++k) {
            unsigned lo = f2bf(wr[2*k]);
            unsigned hi = f2bf(wr[2*k + 1]);
            wrow[k] = lo | (hi << 16);
        }
    }
    __shared__ __align__(16) float h_lds[2][HH];
    __shared__ float act_lds[4][2][HH];
    if (tid < 256) h_lds[tid >> 7][tid & 127] = 0.f;
    float creg = 0.f;
    __syncthreads();

    for (int s = 0; s < TT; ++s) {
        int t = dir ? (TT - 1 - s) : s;
        float acc0 = 0.f, acc1 = 0.f;
#pragma unroll
        for (int k = 0; k < 64; k += 2) {
            float4 h0 = *reinterpret_cast<const float4*>(&h_lds[0][k << 1]);
            float4 h1 = *reinterpret_cast<const float4*>(&h_lds[1][k << 1]);
            unsigned u0 = wrow[k], u1 = wrow[k + 1];
            float w0 = bf_lo(u0), w1 = bf_hi(u0), w2 = bf_lo(u1), w3 = bf_hi(u1);
            acc0 += h0.x*w0 + h0.y*w1 + h0.z*w2 + h0.w*w3;
            acc1 += h1.x*w0 + h1.y*w1 + h1.z*w2 + h1.w*w3;
        }
        float x0 = bfu2f(xg[(((size_t)b0    )*TT + t)*G4 + tid]);
        float x1 = bfu2f(xg[(((size_t)b0 + 1)*TT + t)*G4 + tid]);
        float p0 = acc0 + x0, p1 = acc1 + x1;
        float a0, a1;
        if (gate == 2) { a0 = ftanh(p0);    a1 = ftanh(p1); }
        else           { a0 = fsigmoid(p0); a1 = fsigmoid(p1); }
        act_lds[gate][0][tid & 127] = a0;
        act_lds[gate][1][tid & 127] = a1;
        __syncthreads();
        if (tid < 256) {
            int ub = tid >> 7, uj = tid & 127;
            float iv = act_lds[0][ub][uj];
            float fv = act_lds[1][ub][uj];
            float gv = act_lds[2][ub][uj];
            float ov = act_lds[3][ub][uj];
            creg = fv*creg + iv*gv;
            float hv = ov * ftanh(creg);
            h_lds[ub][uj] = hv;
            hfb[(((size_t)(b0 + ub))*TT + t)*256 + dir*HH + uj] = (ushort)f2bf(hv);
        }
        __syncthreads();
    }
}

// ---------------- logits = feat @ cls_w^T + cls_b ----------------
__global__ __launch_bounds__(256) void logits_kernel(
    const float* __restrict__ feat, const float* __restrict__ cw,
    const float* __restrict__ cb, float* __restrict__ lg)
{
    __shared__ float wls[NK*256];
    for (int i = threadIdx.x; i < NK*256; i += 256) wls[i] = cw[i];
    __syncthreads();
    size_t row = (size_t)blockIdx.x*256 + threadIdx.x;
    const float* fr = &feat[row*256];
    float acc[NK];
#pragma unroll
    for (int k = 0; k < NK; ++k) acc[k] = 0.f;
    for (int c = 0; c < 256; c += 4) {
        float4 v = *reinterpret_cast<const float4*>(&fr[c]);
#pragma unroll
        for (int k = 0; k < NK; ++k)
            acc[k] += v.x*wls[k*256 + c] + v.y*wls[k*256 + c + 1]
                    + v.z*wls[k*256 + c + 2] + v.w*wls[k*256 + c + 3];
    }
#pragma unroll
    for (int k = 0; k < NK; ++k) lg[row*NK + k] = acc[k] + cb[k];
}

// ---------------- weighted CE over all positions ----------------
__global__ __launch_bounds__(256) void ce_kernel(
    const float* __restrict__ lg, const int* __restrict__ labels,
    const float* __restrict__ cw, float* __restrict__ acc2)
{
    size_t i = (size_t)blockIdx.x*256 + threadIdx.x;
    const float* l = &lg[i*NK];
    float mx = -1e30f;
#pragma unroll
    for (int k = 0; k < NK; ++k) mx = fmaxf(mx, l[k]);
    float se = 0.f;
#pragma unroll
    for (int k = 0; k < NK; ++k) se += expf(l[k] - mx);
    float lz = mx + logf(se);
    int y = labels[i];
    bool valid = (y != -100);
    int yi = valid ? y : 0;
    float nll = lz - l[yi];
    float wv = valid ? cw[yi] : 0.f;
    __shared__ float s1[256], s2[256];
    s1[threadIdx.x] = wv*nll;
    s2[threadIdx.x] = wv;
    __syncthreads();
    for (int s = 128; s > 0; s >>= 1) {
        if (threadIdx.x < s) { s1[threadIdx.x] += s1[threadIdx.x + s]; s2[threadIdx.x] += s2[threadIdx.x + s]; }
        __syncthreads();
    }
    if (threadIdx.x == 0) { atomicAdd(&acc2[0], s1[0]); atomicAdd(&acc2[1], s2[0]); }
}

// ---------------- CRF: one wave per sequence ----------------
__global__ __launch_bounds__(64) void crf_kernel(
    const float* __restrict__ lg, const int* __restrict__ att,
    const int* __restrict__ labels, const float* __restrict__ startv,
    const float* __restrict__ trans, const float* __restrict__ endv,
    float* __restrict__ numo, float* __restrict__ logzo)
{
    int b = blockIdx.x;
    int lane = threadIdx.x;
    int lane_c = (lane < NK) ? lane : 0;
    const float* em = &lg[(size_t)b*TT*NK];
    float tr[NK];
#pragma unroll
    for (int i = 0; i < NK; ++i) tr[i] = trans[i*NK + lane_c];
    float score = startv[lane_c] + em[lane_c];

    for (int t = 1; t < TT; ++t) {
        int lt = labels[b*TT + t];
        bool m = (att[b*TT + t] != 0) && (lt != -100);
        float vals[NK];
#pragma unroll
        for (int i = 0; i < NK; ++i)
            vals[i] = __shfl(score, i, 64) + tr[i];
        if (m) {
            float mx = vals[0];
#pragma unroll
            for (int i = 1; i < NK; ++i) mx = fmaxf(mx, vals[i]);
            float sm = 0.f;
#pragma unroll
            for (int i = 0; i < NK; ++i) sm += expf(vals[i] - mx);
            score = mx + logf(sm) + em[t*NK + lane_c];
        }
    }
    float fin = (lane < NK) ? (score + endv[lane_c]) : -1e30f;
    float mx = -1e30f;
#pragma unroll
    for (int i = 0; i < NK; ++i) mx = fmaxf(mx, __shfl(fin, i, 64));
    float sm = 0.f;
#pragma unroll
    for (int i = 0; i < NK; ++i) sm += expf(__shfl(fin, i, 64) - mx);
    if (lane == 0) logzo[b] = mx + logf(sm);

    if (lane == 0) {
        int l0 = labels[b*TT];
        int tag0 = (l0 == -100) ? 0 : l0;
        bool m0 = (att[b*TT] != 0) && (l0 != -100);
        float num = startv[tag0] + em[tag0];
        int prev = tag0;
        int cnt = m0 ? 1 : 0;
        for (int t = 1; t < TT; ++t) {
            int lt = labels[b*TT + t];
            bool m = (att[b*TT + t] != 0) && (lt != -100);
            int tag = (lt == -100) ? 0 : lt;
            if (m) { num += trans[prev*NK + tag] + em[t*NK + tag]; cnt++; }
            prev = tag;
        }
        int le = cnt - 1; if (le < 0) le = 0; if (le >= TT) le = TT - 1;
        int ll = labels[b*TT + le];
        int ltag = (ll == -100) ? 0 : ll;
        num += endv[ltag];
        numo[b] = num;
    }
}

__global__ __launch_bounds__(256) void finalize_kernel(
    const float* __restrict__ numo, const float* __restrict__ logzo,
    const float* __restrict__ acc2, float* __restrict__ out)
{
    __shared__ float red[256];
    int tid = threadIdx.x;
    red[tid] = numo[tid] - logzo[tid];
    __syncthreads();
    for (int s = 128; s > 0; s >>= 1) {
        if (tid < s) red[tid] += red[tid + s];
        __syncthreads();
    }
    if (tid == 0) {
        float crf = -(red[0] / (float)BB);
        float ce = acc2[0] / acc2[1];
        out[0] = 0.8f*crf + 0.2f*ce;
    }
}

extern "C" void kernel_launch(void* const* d_in, const int* in_sizes, int n_in,
                              void* d_out, int out_size, void* d_ws, size_t ws_size,
                              hipStream_t stream)
{
    const float* emb   = (const float*)d_in[0];
    const int*   att   = (const int*)  d_in[1];
    const int*   lab   = (const int*)  d_in[2];
    const float* c5w   = (const float*)d_in[3];
    const float* c5b   = (const float*)d_in[4];
    const float* bn1g  = (const float*)d_in[5];
    const float* bn1b  = (const float*)d_in[6];
    const float* Wihf  = (const float*)d_in[7];
    const float* Whhf  = (const float*)d_in[8];
    const float* bihf  = (const float*)d_in[9];
    const float* bhhf  = (const float*)d_in[10];
    const float* Wihb  = (const float*)d_in[11];
    const float* Whhb  = (const float*)d_in[12];
    const float* bihb  = (const float*)d_in[13];
    const float* bhhb  = (const float*)d_in[14];
    const float* c7w   = (const float*)d_in[15];
    const float* c7b   = (const float*)d_in[16];
    const float* c9w   = (const float*)d_in[17];
    const float* c9b   = (const float*)d_in[18];
    const float* bn2g  = (const float*)d_in[19];
    const float* bn2b  = (const float*)d_in[20];
    const float* clsw  = (const float*)d_in[21];
    const float* clsb  = (const float*)d_in[22];
    const float* cstart= (const float*)d_in[23];
    const float* ctrans= (const float*)d_in[24];
    const float* cend  = (const float*)d_in[25];
    const float* cwts  = (const float*)d_in[26];
    (void)in_sizes; (void)n_in; (void)out_size; (void)ws_size;

    char* wsb = (char*)d_ws;
    size_t off = 0;
    auto alloc = [&](size_t bytes) { void* p = wsb + off; off += (bytes + 255) & ~(size_t)255; return p; };
    float*  y1      = (float*) alloc((size_t)4194304*4);   // (B*T,128) f32
    ushort* xg      = (ushort*)alloc((size_t)2*16777216*2);// [dir][B*T][512] bf16
    float*  c79     = (float*) xg;                         // aliases dir-0 half (dead after lstm)
    ushort* hfb     = (ushort*)alloc((size_t)8388608*2);   // (B*T,256) bf16
    float*  lg      = (float*) alloc((size_t)294912*4);
    ushort* Wk5     = (ushort*)alloc((size_t)655360*2);
    ushort* Wk7     = (ushort*)alloc((size_t)229376*2);
    ushort* Wk9     = (ushort*)alloc((size_t)294912*2);
    ushort* Wxg     = (ushort*)alloc((size_t)131072*2);
    float*  bias_xg = (float*) alloc((size_t)1024*4);
    float*  stats   = (float*) alloc((size_t)2048*4);
    float* bn1s = stats;
    float* bn1q = stats + 128;
    float* bn2s = stats + 256;
    float* bn2q = stats + 512;
    float* acc2 = stats + 768;   // [0]=sum w*nll, [1]=sum w
    float* numo = stats + 770;
    float* logzo = numo + 256;

    hipMemsetAsync(stats, 0, 770*sizeof(float), stream);

    prep_convw_kernel<<<2560, 256, 0, stream>>>(c5w, Wk5, 1024, 5, 655360);
    prep_convw_kernel<<<896,  256, 0, stream>>>(c7w, Wk7, 256, 7, 229376);
    prep_convw_kernel<<<1152, 256, 0, stream>>>(c9w, Wk9, 256, 9, 294912);
    prep_xg_kernel<<<516, 256, 0, stream>>>(Wihf, Wihb, bihf, bhhf, bihb, bhhb, Wxg, bias_xg);

    conv_mfma_kernel<1024,5,true,false><<<dim3(256,1), 256, 0, stream>>>(emb, Wk5, c5b, y1, 128, 0);
    bn_stats_kernel<<<256, 256, 0, stream>>>(y1, 128, 128, bn1s, bn1q);
    bn_gelu_kernel<<<16384, 256, 0, stream>>>(y1, 127, bn1s, bn1q, bn1g, bn1b, 1.0f/32768.f);

    conv_mfma_kernel<128,1,true,true><<<dim3(256,8), 256, 0, stream>>>(y1, Wxg, bias_xg, xg, 512, (size_t)16777216);
    lstm_kernel<<<256, 512, 0, stream>>>(xg, xg + 16777216, Whhf, Whhb, hfb);

    conv_mfma_kernel<256,7,false,false><<<dim3(256,1), 256, 0, stream>>>(hfb, Wk7, c7b, c79, 256, 0);
    conv_mfma_kernel<256,9,false,false><<<dim3(256,1), 256, 0, stream>>>(hfb, Wk9, c9b, c79 + 128, 256, 0);
    bn_stats_kernel<<<256, 256, 0, stream>>>(c79, 256, 128, bn2s, bn2q);
    bn_gelu_kernel<<<32768, 256, 0, stream>>>(c79, 255, bn2s, bn2q, bn2g, bn2b, 1.0f/32768.f);

    logits_kernel<<<128, 256, 0, stream>>>(c79, clsw, clsb, lg);
    ce_kernel<<<128, 256, 0, stream>>>(lg, lab, cwts, acc2);
    crf_kernel<<<BB, 64, 0, stream>>>(lg, att, lab, cstart, ctrans, cend, numo, logzo);
    finalize_kernel<<<1, 256, 0, stream>>>(numo, logzo, acc2, (float*)d_out);
}

// Round 3
// 725.683 us; speedup vs baseline: 3.2287x; 1.1716x over previous
//
#include <hip/hip_runtime.h>
#include <hip/hip_bf16.h>
#include <math.h>

#define BB 256
#define TT 128
#define DD 1024
#define CFF 128
#define HH 128
#define G4 512
#define NK 9

typedef __attribute__((ext_vector_type(8))) short bf16x8;
typedef __attribute__((ext_vector_type(4))) float f32x4;

__device__ __forceinline__ float bfu2f(ushort u){ union{unsigned u; float f;} v; v.u = ((unsigned)u) << 16; return v.f; }
__device__ __forceinline__ unsigned f2bf(float x){
    union{float f; unsigned u;} v; v.f = x;
    unsigned r = v.u + 0x7fffu + ((v.u >> 16) & 1u);
    return r >> 16;
}
__device__ __forceinline__ float fsigmoid(float x){ return 1.0f/(1.0f + __expf(-x)); }
__device__ __forceinline__ float ftanh(float x){
    float a = fabsf(x);
    float e = __expf(-2.0f*a);
    float r = (1.0f - e)/(1.0f + e);
    return x >= 0.f ? r : -r;
}
__device__ __forceinline__ float gelu_exact(float x){
    return 0.5f*x*(1.0f + erff(x*0.70710678118654752440f));
}

// ---------------- weight prep: w[f][d][k] (f32) -> Wk[(k*128+f)*CIN+d] (bf16) ----------------
__global__ __launch_bounds__(256) void prep_convw_kernel(
    const float* __restrict__ w, ushort* __restrict__ Wk, int CIN, int KS, int total)
{
    int i = blockIdx.x*256 + threadIdx.x;
    if (i >= total) return;
    int k = i % KS;
    int d = (i / KS) % CIN;
    int f = i / (KS * CIN);
    Wk[((size_t)(k*128 + f))*CIN + d] = (ushort)f2bf(w[i]);
}

// ---------------- xg weight/bias prep ----------------
__global__ __launch_bounds__(256) void prep_xg_kernel(
    const float* __restrict__ Wf, const float* __restrict__ Wb,
    const float* __restrict__ bif, const float* __restrict__ bhf,
    const float* __restrict__ bib, const float* __restrict__ bhb,
    ushort* __restrict__ Wxg, float* __restrict__ bias_xg)
{
    int i = blockIdx.x*256 + threadIdx.x;
    if (i < 65536) Wxg[i] = (ushort)f2bf(Wf[i]);
    else if (i < 131072) Wxg[i] = (ushort)f2bf(Wb[i - 65536]);
    else {
        int j = i - 131072;
        if (j < 512) bias_xg[j] = bif[j] + bhf[j];
        else if (j < 1024) bias_xg[j] = bib[j-512] + bhb[j-512];
    }
}

// ---------------- implicit-GEMM conv via MFMA ----------------
template<int CIN, int KS, bool IN_F32, bool OUT_BF16>
__global__ __launch_bounds__(256) void conv_mfma_kernel(
    const void* __restrict__ in_v,
    const ushort* __restrict__ Wk_g,
    const float* __restrict__ bias_g,
    void* __restrict__ out_v,
    int OS, size_t out_dir_stride)
{
    constexpr int PAD = KS / 2;
    constexpr int ROWS = 128 + 2 * PAD;
    constexpr int AST = 40;
    constexpr int NSTEP = CIN / 32;
    __shared__ ushort A_lds[ROWS * AST];
    __shared__ ushort B_lds[KS * 128 * AST];

    const int tid = threadIdx.x;
    const size_t row0 = (size_t)blockIdx.x * 128;
    const int by = blockIdx.y;
    const ushort* __restrict__ Wk = Wk_g + (size_t)by * 16384;
    const float* __restrict__ bias = bias_g + (size_t)by * 128;

    f32x4 acc[4][4];
#pragma unroll
    for (int m = 0; m < 4; ++m)
#pragma unroll
        for (int n = 0; n < 4; ++n)
            acc[m][n] = (f32x4){0.f, 0.f, 0.f, 0.f};

    if (PAD > 0) {
        for (int i = tid; i < PAD * AST; i += 256) {
            A_lds[i] = 0;
            A_lds[(PAD + 128) * AST + i] = 0;
        }
    }

    const int lane = tid & 63;
    const int wave = tid >> 6;
    const int lr = lane & 15;
    const int lk = lane >> 4;
    const int wm = wave >> 1;
    const int wn = wave & 1;
    const int abase = (wm * 64 + lr) * AST + lk * 8;

    for (int s = 0; s < NSTEP; ++s) {
        const int d0 = s * 32;
        __syncthreads();
        if constexpr (IN_F32) {
            const float* __restrict__ inp = (const float*)in_v;
            for (int i = tid; i < 1024; i += 256) {
                int r = i >> 3, c = i & 7;
                float4 v = *reinterpret_cast<const float4*>(&inp[(row0 + r) * CIN + d0 + c * 4]);
                ushort4 h;
                h.x = (ushort)f2bf(v.x); h.y = (ushort)f2bf(v.y);
                h.z = (ushort)f2bf(v.z); h.w = (ushort)f2bf(v.w);
                *reinterpret_cast<ushort4*>(&A_lds[(PAD + r) * AST + c * 4]) = h;
            }
        } else {
            const ushort* __restrict__ inp = (const ushort*)in_v;
            for (int i = tid; i < 512; i += 256) {
                int r = i >> 2, c = i & 3;
                int4 v = *reinterpret_cast<const int4*>(&inp[(row0 + r) * CIN + d0 + c * 8]);
                *reinterpret_cast<int4*>(&A_lds[(PAD + r) * AST + c * 8]) = v;
            }
        }
        for (int i = tid; i < KS * 128 * 4; i += 256) {
            int k = i >> 9;
            int rem = i & 511;
            int f = rem >> 2, c = rem & 3;
            int4 v = *reinterpret_cast<const int4*>(&Wk[((size_t)((k << 7) + f)) * CIN + d0 + c * 8]);
            *reinterpret_cast<int4*>(&B_lds[((k << 7) + f) * AST + c * 8]) = v;
        }
        __syncthreads();
#pragma unroll
        for (int k = 0; k < KS; ++k) {
            bf16x8 af[4], bfr[4];
#pragma unroll
            for (int m = 0; m < 4; ++m)
                af[m] = *reinterpret_cast<const bf16x8*>(&A_lds[abase + (m * 16 + k) * AST]);
#pragma unroll
            for (int n = 0; n < 4; ++n)
                bfr[n] = *reinterpret_cast<const bf16x8*>(&B_lds[((k << 7) + wn * 64 + n * 16 + lr) * AST + lk * 8]);
#pragma unroll
            for (int m = 0; m < 4; ++m)
#pragma unroll
                for (int n = 0; n < 4; ++n)
                    acc[m][n] = __builtin_amdgcn_mfma_f32_16x16x32_bf16(af[m], bfr[n], acc[m][n], 0, 0, 0);
        }
    }

    float bv[4];
#pragma unroll
    for (int n = 0; n < 4; ++n) bv[n] = bias[wn * 64 + n * 16 + lr];
    size_t out_off = (size_t)(by >> 2) * out_dir_stride + (size_t)(by & 3) * 128;
#pragma unroll
    for (int m = 0; m < 4; ++m) {
#pragma unroll
        for (int n = 0; n < 4; ++n) {
            int f = wn * 64 + n * 16 + lr;
#pragma unroll
            for (int j = 0; j < 4; ++j) {
                int t = wm * 64 + m * 16 + lk * 4 + j;
                float val = acc[m][n][j] + bv[n];
                if constexpr (OUT_BF16)
                    ((ushort*)out_v)[out_off + (row0 + t) * (size_t)OS + f] = (ushort)f2bf(val);
                else
                    ((float*)out_v)[out_off + (row0 + t) * (size_t)OS + f] = val;
            }
        }
    }
}

// ---------------- BN stats ----------------
__global__ __launch_bounds__(256) void bn_stats_kernel(
    const float* __restrict__ y, int C, int rows_per_blk,
    float* __restrict__ sum, float* __restrict__ sqsum)
{
    int tpc = 256 / C;
    int c = threadIdx.x & (C - 1);
    int sub = threadIdx.x / C;
    size_t r0 = (size_t)blockIdx.x * rows_per_blk;
    float s = 0.f, s2 = 0.f;
    for (int r = sub; r < rows_per_blk; r += tpc) {
        float v = y[(r0 + r)*C + c];
        s += v; s2 += v*v;
    }
    __shared__ float ls[256], ls2[256];
    ls[threadIdx.x] = s; ls2[threadIdx.x] = s2;
    __syncthreads();
    if (sub == 0) {
        for (int k = 1; k < tpc; ++k) { s += ls[c + k*C]; s2 += ls2[c + k*C]; }
        atomicAdd(&sum[c], s);
        atomicAdd(&sqsum[c], s2);
    }
}

__global__ __launch_bounds__(256) void bn_gelu_kernel(
    float* __restrict__ y, int Cmask, const float* __restrict__ sum,
    const float* __restrict__ sqsum, const float* __restrict__ g,
    const float* __restrict__ beta, float inv_n)
{
    size_t i = (size_t)blockIdx.x*256 + threadIdx.x;
    int c = (int)(i & (size_t)Cmask);
    float m = sum[c] * inv_n;
    float var = fmaxf(sqsum[c]*inv_n - m*m, 0.f);
    float xv = (y[i] - m) * rsqrtf(var + 1e-5f) * g[c] + beta[c];
    y[i] = gelu_exact(xv);
}

// ---------------- MFMA bi-LSTM: 32 blocks x 16 sequences ----------------
// Whh held in registers as MFMA B-fragments; one barrier/step; xg prefetched.
__global__ __launch_bounds__(512, 1) void lstm_mfma_kernel(
    const ushort* __restrict__ xg_g,   // [dir][b*T][512] bf16
    const float* __restrict__ Whhf, const float* __restrict__ Whhb,
    ushort* __restrict__ hfb)          // [b*T][256] bf16
{
    const int tid = threadIdx.x;
    const int lane = tid & 63;
    const int w = tid >> 6;            // wave 0..7 -> hidden cols w*16..w*16+15
    const int dir = blockIdx.x >> 4;
    const int b0 = (blockIdx.x & 15) << 4;
    const ushort* __restrict__ xg = xg_g + (size_t)dir * 16777216;
    const float* __restrict__ Whh = dir ? Whhb : Whhf;

    const int jc = lane & 15;
    const int j  = (w << 4) + jc;      // hidden col 0..127 (also N-col via n=g*128+j)
    const int kq = lane >> 4;          // k-chunk / acc-row-quarter
    const int mb = kq << 2;            // batch row base for acc regs

    // ---- load Whh into registers as B fragments: B[g][s] = Whh[g*128+j][s*32+kq*8 ..+8]
    bf16x8 Bf[4][4];
#pragma unroll
    for (int g = 0; g < 4; ++g) {
        const float* wr = &Whh[(size_t)((g << 7) + j) * HH];
#pragma unroll
        for (int s = 0; s < 4; ++s) {
            const float* p = wr + (s << 5) + (kq << 3);
            float4 v0 = *reinterpret_cast<const float4*>(p);
            float4 v1 = *reinterpret_cast<const float4*>(p + 4);
            union { bf16x8 v; ushort u[8]; } pk;
            pk.u[0] = (ushort)f2bf(v0.x); pk.u[1] = (ushort)f2bf(v0.y);
            pk.u[2] = (ushort)f2bf(v0.z); pk.u[3] = (ushort)f2bf(v0.w);
            pk.u[4] = (ushort)f2bf(v1.x); pk.u[5] = (ushort)f2bf(v1.y);
            pk.u[6] = (ushort)f2bf(v1.z); pk.u[7] = (ushort)f2bf(v1.w);
            Bf[g][s] = pk.v;
        }
    }

    __shared__ ushort h_lds[2][16 * 136];   // [buf][batch][hidden], padded stride 136
    for (int i = tid; i < 16 * 136; i += 512) h_lds[0][i] = 0;
    float creg[4] = {0.f, 0.f, 0.f, 0.f};

    // prefetch xg for first step
    int tt0 = dir ? (TT - 1) : 0;
    ushort xr[16];
#pragma unroll
    for (int g = 0; g < 4; ++g)
#pragma unroll
        for (int r = 0; r < 4; ++r)
            xr[g*4+r] = xg[((size_t)(b0 + mb + r) * TT + tt0) * G4 + (g << 7) + j];

    __syncthreads();

    int cur = 0;
    for (int t = 0; t < TT; ++t) {
        const int tt_c = dir ? (TT - 1 - t) : t;
        const int tn   = (t < TT - 1) ? (t + 1) : (TT - 1);
        const int tt_n = dir ? (TT - 1 - tn) : tn;

        // A fragments: A[m=batch=lane&15][k = s*32 + kq*8]
        bf16x8 Af[4];
#pragma unroll
        for (int s = 0; s < 4; ++s)
            Af[s] = *reinterpret_cast<const bf16x8*>(&h_lds[cur][jc * 136 + (s << 5) + (kq << 3)]);

        f32x4 acc[4];
#pragma unroll
        for (int g = 0; g < 4; ++g) acc[g] = (f32x4){0.f, 0.f, 0.f, 0.f};
#pragma unroll
        for (int s = 0; s < 4; ++s)
#pragma unroll
            for (int g = 0; g < 4; ++g)
                acc[g] = __builtin_amdgcn_mfma_f32_16x16x32_bf16(Af[s], Bf[g][s], acc[g], 0, 0, 0);

        // gates + cell update (all 4 gates of (b,j) live in this thread at reg r)
        ushort hb[4];
#pragma unroll
        for (int r = 0; r < 4; ++r) {
            float gi = acc[0][r] + bfu2f(xr[r]);
            float gf = acc[1][r] + bfu2f(xr[4 + r]);
            float gg = acc[2][r] + bfu2f(xr[8 + r]);
            float go = acc[3][r] + bfu2f(xr[12 + r]);
            float iv = fsigmoid(gi), fv = fsigmoid(gf);
            float gv = ftanh(gg),    ov = fsigmoid(go);
            creg[r] = fv * creg[r] + iv * gv;
            float hv = ov * ftanh(creg[r]);
            hb[r] = (ushort)f2bf(hv);
        }

        const int nxt = cur ^ 1;
#pragma unroll
        for (int r = 0; r < 4; ++r) {
            h_lds[nxt][(mb + r) * 136 + j] = hb[r];
            hfb[((size_t)(b0 + mb + r) * TT + tt_c) * 256 + (dir << 7) + j] = hb[r];
        }
        // prefetch xg for next step (hidden under next step's MFMA)
#pragma unroll
        for (int g = 0; g < 4; ++g)
#pragma unroll
            for (int r = 0; r < 4; ++r)
                xr[g*4+r] = xg[((size_t)(b0 + mb + r) * TT + tt_n) * G4 + (g << 7) + j];

        __syncthreads();
        cur = nxt;
    }
}

// ---------------- logits = feat @ cls_w^T + cls_b ----------------
__global__ __launch_bounds__(256) void logits_kernel(
    const float* __restrict__ feat, const float* __restrict__ cw,
    const float* __restrict__ cb, float* __restrict__ lg)
{
    __shared__ float wls[NK*256];
    for (int i = threadIdx.x; i < NK*256; i += 256) wls[i] = cw[i];
    __syncthreads();
    size_t row = (size_t)blockIdx.x*256 + threadIdx.x;
    const float* fr = &feat[row*256];
    float acc[NK];
#pragma unroll
    for (int k = 0; k < NK; ++k) acc[k] = 0.f;
    for (int c = 0; c < 256; c += 4) {
        float4 v = *reinterpret_cast<const float4*>(&fr[c]);
#pragma unroll
        for (int k = 0; k < NK; ++k)
            acc[k] += v.x*wls[k*256 + c] + v.y*wls[k*256 + c + 1]
                    + v.z*wls[k*256 + c + 2] + v.w*wls[k*256 + c + 3];
    }
#pragma unroll
    for (int k = 0; k < NK; ++k) lg[row*NK + k] = acc[k] + cb[k];
}

// ---------------- weighted CE ----------------
__global__ __launch_bounds__(256) void ce_kernel(
    const float* __restrict__ lg, const int* __restrict__ labels,
    const float* __restrict__ cw, float* __restrict__ acc2)
{
    size_t i = (size_t)blockIdx.x*256 + threadIdx.x;
    const float* l = &lg[i*NK];
    float mx = -1e30f;
#pragma unroll
    for (int k = 0; k < NK; ++k) mx = fmaxf(mx, l[k]);
    float se = 0.f;
#pragma unroll
    for (int k = 0; k < NK; ++k) se += expf(l[k] - mx);
    float lz = mx + logf(se);
    int y = labels[i];
    bool valid = (y != -100);
    int yi = valid ? y : 0;
    float nll = lz - l[yi];
    float wv = valid ? cw[yi] : 0.f;
    __shared__ float s1[256], s2[256];
    s1[threadIdx.x] = wv*nll;
    s2[threadIdx.x] = wv;
    __syncthreads();
    for (int s = 128; s > 0; s >>= 1) {
        if (threadIdx.x < s) { s1[threadIdx.x] += s1[threadIdx.x + s]; s2[threadIdx.x] += s2[threadIdx.x + s]; }
        __syncthreads();
    }
    if (threadIdx.x == 0) { atomicAdd(&acc2[0], s1[0]); atomicAdd(&acc2[1], s2[0]); }
}

// ---------------- CRF ----------------
__global__ __launch_bounds__(64) void crf_kernel(
    const float* __restrict__ lg, const int* __restrict__ att,
    const int* __restrict__ labels, const float* __restrict__ startv,
    const float* __restrict__ trans, const float* __restrict__ endv,
    float* __restrict__ numo, float* __restrict__ logzo)
{
    int b = blockIdx.x;
    int lane = threadIdx.x;
    int lane_c = (lane < NK) ? lane : 0;
    const float* em = &lg[(size_t)b*TT*NK];
    float tr[NK];
#pragma unroll
    for (int i = 0; i < NK; ++i) tr[i] = trans[i*NK + lane_c];
    float score = startv[lane_c] + em[lane_c];

    for (int t = 1; t < TT; ++t) {
        int lt = labels[b*TT + t];
        bool m = (att[b*TT + t] != 0) && (lt != -100);
        float vals[NK];
#pragma unroll
        for (int i = 0; i < NK; ++i)
            vals[i] = __shfl(score, i, 64) + tr[i];
        if (m) {
            float mx = vals[0];
#pragma unroll
            for (int i = 1; i < NK; ++i) mx = fmaxf(mx, vals[i]);
            float sm = 0.f;
#pragma unroll
            for (int i = 0; i < NK; ++i) sm += expf(vals[i] - mx);
            score = mx + logf(sm) + em[t*NK + lane_c];
        }
    }
    float fin = (lane < NK) ? (score + endv[lane_c]) : -1e30f;
    float mx = -1e30f;
#pragma unroll
    for (int i = 0; i < NK; ++i) mx = fmaxf(mx, __shfl(fin, i, 64));
    float sm = 0.f;
#pragma unroll
    for (int i = 0; i < NK; ++i) sm += expf(__shfl(fin, i, 64) - mx);
    if (lane == 0) logzo[b] = mx + logf(sm);

    if (lane == 0) {
        int l0 = labels[b*TT];
        int tag0 = (l0 == -100) ? 0 : l0;
        bool m0 = (att[b*TT] != 0) && (l0 != -100);
        float num = startv[tag0] + em[tag0];
        int prev = tag0;
        int cnt = m0 ? 1 : 0;
        for (int t = 1; t < TT; ++t) {
            int lt = labels[b*TT + t];
            bool m = (att[b*TT + t] != 0) && (lt != -100);
            int tag = (lt == -100) ? 0 : lt;
            if (m) { num += trans[prev*NK + tag] + em[t*NK + tag]; cnt++; }
            prev = tag;
        }
        int le = cnt - 1; if (le < 0) le = 0; if (le >= TT) le = TT - 1;
        int ll = labels[b*TT + le];
        int ltag = (ll == -100) ? 0 : ll;
        num += endv[ltag];
        numo[b] = num;
    }
}

__global__ __launch_bounds__(256) void finalize_kernel(
    const float* __restrict__ numo, const float* __restrict__ logzo,
    const float* __restrict__ acc2, float* __restrict__ out)
{
    __shared__ float red[256];
    int tid = threadIdx.x;
    red[tid] = numo[tid] - logzo[tid];
    __syncthreads();
    for (int s = 128; s > 0; s >>= 1) {
        if (tid < s) red[tid] += red[tid + s];
        __syncthreads();
    }
    if (tid == 0) {
        float crf = -(red[0] / (float)BB);
        float ce = acc2[0] / acc2[1];
        out[0] = 0.8f*crf + 0.2f*ce;
    }
}

extern "C" void kernel_launch(void* const* d_in, const int* in_sizes, int n_in,
                              void* d_out, int out_size, void* d_ws, size_t ws_size,
                              hipStream_t stream)
{
    const float* emb   = (const float*)d_in[0];
    const int*   att   = (const int*)  d_in[1];
    const int*   lab   = (const int*)  d_in[2];
    const float* c5w   = (const float*)d_in[3];
    const float* c5b   = (const float*)d_in[4];
    const float* bn1g  = (const float*)d_in[5];
    const float* bn1b  = (const float*)d_in[6];
    const float* Wihf  = (const float*)d_in[7];
    const float* Whhf  = (const float*)d_in[8];
    const float* bihf  = (const float*)d_in[9];
    const float* bhhf  = (const float*)d_in[10];
    const float* Wihb  = (const float*)d_in[11];
    const float* Whhb  = (const float*)d_in[12];
    const float* bihb  = (const float*)d_in[13];
    const float* bhhb  = (const float*)d_in[14];
    const float* c7w   = (const float*)d_in[15];
    const float* c7b   = (const float*)d_in[16];
    const float* c9w   = (const float*)d_in[17];
    const float* c9b   = (const float*)d_in[18];
    const float* bn2g  = (const float*)d_in[19];
    const float* bn2b  = (const float*)d_in[20];
    const float* clsw  = (const float*)d_in[21];
    const float* clsb  = (const float*)d_in[22];
    const float* cstart= (const float*)d_in[23];
    const float* ctrans= (const float*)d_in[24];
    const float* cend  = (const float*)d_in[25];
    const float* cwts  = (const float*)d_in[26];
    (void)in_sizes; (void)n_in; (void)out_size; (void)ws_size;

    char* wsb = (char*)d_ws;
    size_t off = 0;
    auto alloc = [&](size_t bytes) { void* p = wsb + off; off += (bytes + 255) & ~(size_t)255; return p; };
    float*  y1      = (float*) alloc((size_t)4194304*4);   // (B*T,128) f32
    ushort* xg      = (ushort*)alloc((size_t)2*16777216*2);// [dir][B*T][512] bf16
    float*  c79     = (float*) xg;                         // aliases dir-0 half (dead after lstm)
    ushort* hfb     = (ushort*)alloc((size_t)8388608*2);   // (B*T,256) bf16
    float*  lg      = (float*) alloc((size_t)294912*4);
    ushort* Wk5     = (ushort*)alloc((size_t)655360*2);
    ushort* Wk7     = (ushort*)alloc((size_t)229376*2);
    ushort* Wk9     = (ushort*)alloc((size_t)294912*2);
    ushort* Wxg     = (ushort*)alloc((size_t)131072*2);
    float*  bias_xg = (float*) alloc((size_t)1024*4);
    float*  stats   = (float*) alloc((size_t)2048*4);
    float* bn1s = stats;
    float* bn1q = stats + 128;
    float* bn2s = stats + 256;
    float* bn2q = stats + 512;
    float* acc2 = stats + 768;
    float* numo = stats + 770;
    float* logzo = numo + 256;

    hipMemsetAsync(stats, 0, 770*sizeof(float), stream);

    prep_convw_kernel<<<2560, 256, 0, stream>>>(c5w, Wk5, 1024, 5, 655360);
    prep_convw_kernel<<<896,  256, 0, stream>>>(c7w, Wk7, 256, 7, 229376);
    prep_convw_kernel<<<1152, 256, 0, stream>>>(c9w, Wk9, 256, 9, 294912);
    prep_xg_kernel<<<516, 256, 0, stream>>>(Wihf, Wihb, bihf, bhhf, bihb, bhhb, Wxg, bias_xg);

    conv_mfma_kernel<1024,5,true,false><<<dim3(256,1), 256, 0, stream>>>(emb, Wk5, c5b, y1, 128, 0);
    bn_stats_kernel<<<256, 256, 0, stream>>>(y1, 128, 128, bn1s, bn1q);
    bn_gelu_kernel<<<16384, 256, 0, stream>>>(y1, 127, bn1s, bn1q, bn1g, bn1b, 1.0f/32768.f);

    conv_mfma_kernel<128,1,true,true><<<dim3(256,8), 256, 0, stream>>>(y1, Wxg, bias_xg, xg, 512, (size_t)16777216);
    lstm_mfma_kernel<<<32, 512, 0, stream>>>(xg, Whhf, Whhb, hfb);

    conv_mfma_kernel<256,7,false,false><<<dim3(256,1), 256, 0, stream>>>(hfb, Wk7, c7b, c79, 256, 0);
    conv_mfma_kernel<256,9,false,false><<<dim3(256,1), 256, 0, stream>>>(hfb, Wk9, c9b, c79 + 128, 256, 0);
    bn_stats_kernel<<<256, 256, 0, stream>>>(c79, 256, 128, bn2s, bn2q);
    bn_gelu_kernel<<<32768, 256, 0, stream>>>(c79, 255, bn2s, bn2q, bn2g, bn2b, 1.0f/32768.f);

    logits_kernel<<<128, 256, 0, stream>>>(c79, clsw, clsb, lg);
    ce_kernel<<<128, 256, 0, stream>>>(lg, lab, cwts, acc2);
    crf_kernel<<<BB, 64, 0, stream>>>(lg, att, lab, cstart, ctrans, cend, numo, logzo);
    finalize_kernel<<<1, 256, 0, stream>>>(numo, logzo, acc2, (float*)d_out);
}

// Round 4
// 719.635 us; speedup vs baseline: 3.2559x; 1.0084x over previous
//
#include <hip/hip_runtime.h>
#include <hip/hip_bf16.h>
#include <math.h>

#define BB 256
#define TT 128
#define DD 1024
#define CFF 128
#define HH 128
#define G4 512
#define NK 9

typedef __attribute__((ext_vector_type(8))) short bf16x8;
typedef __attribute__((ext_vector_type(4))) float f32x4;

__device__ __forceinline__ float bfu2f(ushort u){ union{unsigned u; float f;} v; v.u = ((unsigned)u) << 16; return v.f; }
__device__ __forceinline__ unsigned f2bf(float x){
    union{float f; unsigned u;} v; v.f = x;
    unsigned r = v.u + 0x7fffu + ((v.u >> 16) & 1u);
    return r >> 16;
}
__device__ __forceinline__ float fsigmoid(float x){ return 1.0f/(1.0f + __expf(-x)); }
__device__ __forceinline__ float ftanh(float x){
    float a = fabsf(x);
    float e = __expf(-2.0f*a);
    float r = (1.0f - e)/(1.0f + e);
    return x >= 0.f ? r : -r;
}
__device__ __forceinline__ float gelu_exact(float x){
    return 0.5f*x*(1.0f + erff(x*0.70710678118654752440f));
}

// ---------------- weight prep: w[f][d][k] (f32) -> Wk[(k*128+f)*CIN+d] (bf16) ----------------
__global__ __launch_bounds__(256) void prep_convw_kernel(
    const float* __restrict__ w, ushort* __restrict__ Wk, int CIN, int KS, int total)
{
    int i = blockIdx.x*256 + threadIdx.x;
    if (i >= total) return;
    int k = i % KS;
    int d = (i / KS) % CIN;
    int f = i / (KS * CIN);
    Wk[((size_t)(k*128 + f))*CIN + d] = (ushort)f2bf(w[i]);
}

// ---------------- xg weight/bias prep ----------------
__global__ __launch_bounds__(256) void prep_xg_kernel(
    const float* __restrict__ Wf, const float* __restrict__ Wb,
    const float* __restrict__ bif, const float* __restrict__ bhf,
    const float* __restrict__ bib, const float* __restrict__ bhb,
    ushort* __restrict__ Wxg, float* __restrict__ bias_xg)
{
    int i = blockIdx.x*256 + threadIdx.x;
    if (i < 65536) Wxg[i] = (ushort)f2bf(Wf[i]);
    else if (i < 131072) Wxg[i] = (ushort)f2bf(Wb[i - 65536]);
    else {
        int j = i - 131072;
        if (j < 512) bias_xg[j] = bif[j] + bhf[j];
        else if (j < 1024) bias_xg[j] = bib[j-512] + bhb[j-512];
    }
}

// ---------------- implicit-GEMM conv via MFMA ----------------
// XGT=true writes output transposed as [t][b][512] per direction (for LSTM xg).
template<int CIN, int KS, bool IN_F32, bool OUT_BF16, bool XGT = false>
__global__ __launch_bounds__(256) void conv_mfma_kernel(
    const void* __restrict__ in_v,
    const ushort* __restrict__ Wk_g,
    const float* __restrict__ bias_g,
    void* __restrict__ out_v,
    int OS, size_t out_dir_stride)
{
    constexpr int PAD = KS / 2;
    constexpr int ROWS = 128 + 2 * PAD;
    constexpr int AST = 40;
    constexpr int NSTEP = CIN / 32;
    __shared__ ushort A_lds[ROWS * AST];
    __shared__ ushort B_lds[KS * 128 * AST];

    const int tid = threadIdx.x;
    const size_t row0 = (size_t)blockIdx.x * 128;
    const int by = blockIdx.y;
    const ushort* __restrict__ Wk = Wk_g + (size_t)by * 16384;
    const float* __restrict__ bias = bias_g + (size_t)by * 128;

    f32x4 acc[4][4];
#pragma unroll
    for (int m = 0; m < 4; ++m)
#pragma unroll
        for (int n = 0; n < 4; ++n)
            acc[m][n] = (f32x4){0.f, 0.f, 0.f, 0.f};

    if (PAD > 0) {
        for (int i = tid; i < PAD * AST; i += 256) {
            A_lds[i] = 0;
            A_lds[(PAD + 128) * AST + i] = 0;
        }
    }

    const int lane = tid & 63;
    const int wave = tid >> 6;
    const int lr = lane & 15;
    const int lk = lane >> 4;
    const int wm = wave >> 1;
    const int wn = wave & 1;
    const int abase = (wm * 64 + lr) * AST + lk * 8;

    for (int s = 0; s < NSTEP; ++s) {
        const int d0 = s * 32;
        __syncthreads();
        if constexpr (IN_F32) {
            const float* __restrict__ inp = (const float*)in_v;
            for (int i = tid; i < 1024; i += 256) {
                int r = i >> 3, c = i & 7;
                float4 v = *reinterpret_cast<const float4*>(&inp[(row0 + r) * CIN + d0 + c * 4]);
                ushort4 h;
                h.x = (ushort)f2bf(v.x); h.y = (ushort)f2bf(v.y);
                h.z = (ushort)f2bf(v.z); h.w = (ushort)f2bf(v.w);
                *reinterpret_cast<ushort4*>(&A_lds[(PAD + r) * AST + c * 4]) = h;
            }
        } else {
            const ushort* __restrict__ inp = (const ushort*)in_v;
            for (int i = tid; i < 512; i += 256) {
                int r = i >> 2, c = i & 3;
                int4 v = *reinterpret_cast<const int4*>(&inp[(row0 + r) * CIN + d0 + c * 8]);
                *reinterpret_cast<int4*>(&A_lds[(PAD + r) * AST + c * 8]) = v;
            }
        }
        for (int i = tid; i < KS * 128 * 4; i += 256) {
            int k = i >> 9;
            int rem = i & 511;
            int f = rem >> 2, c = rem & 3;
            int4 v = *reinterpret_cast<const int4*>(&Wk[((size_t)((k << 7) + f)) * CIN + d0 + c * 8]);
            *reinterpret_cast<int4*>(&B_lds[((k << 7) + f) * AST + c * 8]) = v;
        }
        __syncthreads();
#pragma unroll
        for (int k = 0; k < KS; ++k) {
            bf16x8 af[4], bfr[4];
#pragma unroll
            for (int m = 0; m < 4; ++m)
                af[m] = *reinterpret_cast<const bf16x8*>(&A_lds[abase + (m * 16 + k) * AST]);
#pragma unroll
            for (int n = 0; n < 4; ++n)
                bfr[n] = *reinterpret_cast<const bf16x8*>(&B_lds[((k << 7) + wn * 64 + n * 16 + lr) * AST + lk * 8]);
#pragma unroll
            for (int m = 0; m < 4; ++m)
#pragma unroll
                for (int n = 0; n < 4; ++n)
                    acc[m][n] = __builtin_amdgcn_mfma_f32_16x16x32_bf16(af[m], bfr[n], acc[m][n], 0, 0, 0);
        }
    }

    float bv[4];
#pragma unroll
    for (int n = 0; n < 4; ++n) bv[n] = bias[wn * 64 + n * 16 + lr];
    size_t out_off = (size_t)(by >> 2) * out_dir_stride + (size_t)(by & 3) * 128;
#pragma unroll
    for (int m = 0; m < 4; ++m) {
#pragma unroll
        for (int n = 0; n < 4; ++n) {
            int f = wn * 64 + n * 16 + lr;
#pragma unroll
            for (int q = 0; q < 4; ++q) {
                int trow = wm * 64 + m * 16 + lk * 4 + q;
                float val = acc[m][n][q] + bv[n];
                size_t idx;
                if constexpr (XGT)
                    idx = out_off + ((size_t)trow * 256 + blockIdx.x) * 512 + f;
                else
                    idx = out_off + (row0 + trow) * (size_t)OS + f;
                if constexpr (OUT_BF16)
                    ((ushort*)out_v)[idx] = (ushort)f2bf(val);
                else
                    ((float*)out_v)[idx] = val;
            }
        }
    }
}

// ---------------- BN stats ----------------
__global__ __launch_bounds__(256) void bn_stats_kernel(
    const float* __restrict__ y, int C, int rows_per_blk,
    float* __restrict__ sum, float* __restrict__ sqsum)
{
    int tpc = 256 / C;
    int c = threadIdx.x & (C - 1);
    int sub = threadIdx.x / C;
    size_t r0 = (size_t)blockIdx.x * rows_per_blk;
    float s = 0.f, s2 = 0.f;
    for (int r = sub; r < rows_per_blk; r += tpc) {
        float v = y[(r0 + r)*C + c];
        s += v; s2 += v*v;
    }
    __shared__ float ls[256], ls2[256];
    ls[threadIdx.x] = s; ls2[threadIdx.x] = s2;
    __syncthreads();
    if (sub == 0) {
        for (int k = 1; k < tpc; ++k) { s += ls[c + k*C]; s2 += ls2[c + k*C]; }
        atomicAdd(&sum[c], s);
        atomicAdd(&sqsum[c], s2);
    }
}

__global__ __launch_bounds__(256) void bn_gelu_kernel(
    float* __restrict__ y, int Cmask, const float* __restrict__ sum,
    const float* __restrict__ sqsum, const float* __restrict__ g,
    const float* __restrict__ beta, float inv_n)
{
    size_t i = (size_t)blockIdx.x*256 + threadIdx.x;
    int c = (int)(i & (size_t)Cmask);
    float m = sum[c] * inv_n;
    float var = fmaxf(sqsum[c]*inv_n - m*m, 0.f);
    float xv = (y[i] - m) * rsqrtf(var + 1e-5f) * g[c] + beta[c];
    y[i] = gelu_exact(xv);
}

// ---------------- MFMA bi-LSTM v2: raw barriers + deep register prefetch ----------------
// xgT layout: [dir][t][b][512] bf16. 32 blocks x 512 thr; Whh in regs as B-frags.
__global__ __launch_bounds__(512, 1) void lstm_mfma_kernel(
    const ushort* __restrict__ xgT,
    const float* __restrict__ Whhf, const float* __restrict__ Whhb,
    ushort* __restrict__ hfb)
{
    const int tid = threadIdx.x;
    const int lane = tid & 63;
    const int w = tid >> 6;            // wave 0..7 -> hidden cols w*16..w*16+15
    const int dir = blockIdx.x >> 4;
    const int b0 = (blockIdx.x & 15) << 4;
    const ushort* __restrict__ xg = xgT + (size_t)dir * ((size_t)TT * 256 * G4);
    const float* __restrict__ Whh = dir ? Whhb : Whhf;

    const int jc = lane & 15;
    const int j  = (w << 4) + jc;
    const int kq = lane >> 4;
    const int mb = kq << 2;

    // Whh B-fragments: B[g][s] = Whh[g*128+j][s*32+kq*8 ..+8]
    bf16x8 Bf[4][4];
#pragma unroll
    for (int g = 0; g < 4; ++g) {
        const float* wr = &Whh[(size_t)((g << 7) + j) * HH];
#pragma unroll
        for (int s = 0; s < 4; ++s) {
            const float* p = wr + (s << 5) + (kq << 3);
            float4 v0 = *reinterpret_cast<const float4*>(p);
            float4 v1 = *reinterpret_cast<const float4*>(p + 4);
            union { bf16x8 v; ushort u[8]; } pk;
            pk.u[0] = (ushort)f2bf(v0.x); pk.u[1] = (ushort)f2bf(v0.y);
            pk.u[2] = (ushort)f2bf(v0.z); pk.u[3] = (ushort)f2bf(v0.w);
            pk.u[4] = (ushort)f2bf(v1.x); pk.u[5] = (ushort)f2bf(v1.y);
            pk.u[6] = (ushort)f2bf(v1.z); pk.u[7] = (ushort)f2bf(v1.w);
            Bf[g][s] = pk.v;
        }
    }

    __shared__ ushort h_lds[2][16 * 136];
    for (int i = tid; i < 16 * 136; i += 512) h_lds[0][i] = 0;
    float creg[4] = {0.f, 0.f, 0.f, 0.f};

    // 2-deep xg prefetch (registers). xrA holds even steps, xrB odd steps.
    unsigned xrA[16], xrB[16];
    {
        int tt0 = dir ? (TT - 1) : 0;
        int tt1 = dir ? (TT - 2) : 1;
#pragma unroll
        for (int g = 0; g < 4; ++g)
#pragma unroll
            for (int r = 0; r < 4; ++r) {
                xrA[g*4+r] = xg[((size_t)tt0 * 256 + b0 + mb + r) * G4 + (g << 7) + j];
                xrB[g*4+r] = xg[((size_t)tt1 * 256 + b0 + mb + r) * G4 + (g << 7) + j];
            }
    }

    __syncthreads();   // once: zero-init of h_lds visible to all waves

    int cur = 0;
    auto step = [&](int t, unsigned* xr) {
        const int tt_c = dir ? (TT - 1 - t) : t;
        // A fragments from current h
        bf16x8 Af[4];
#pragma unroll
        for (int s = 0; s < 4; ++s)
            Af[s] = *reinterpret_cast<const bf16x8*>(&h_lds[cur][jc * 136 + (s << 5) + (kq << 3)]);
        // acc init = xg (C-operand of MFMA)
        f32x4 acc[4];
#pragma unroll
        for (int g = 0; g < 4; ++g)
#pragma unroll
            for (int r = 0; r < 4; ++r)
                acc[g][r] = bfu2f((ushort)xr[g*4 + r]);
#pragma unroll
        for (int s = 0; s < 4; ++s)
#pragma unroll
            for (int g = 0; g < 4; ++g)
                acc[g] = __builtin_amdgcn_mfma_f32_16x16x32_bf16(Af[s], Bf[g][s], acc[g], 0, 0, 0);
        // prefetch xg for t+2 (consumed 2 barriers later; never drained at barrier)
        {
            int t2 = (t + 2 < TT) ? (t + 2) : t;
            int tt_n = dir ? (TT - 1 - t2) : t2;
#pragma unroll
            for (int g = 0; g < 4; ++g)
#pragma unroll
                for (int r = 0; r < 4; ++r)
                    xr[g*4 + r] = xg[((size_t)tt_n * 256 + b0 + mb + r) * G4 + (g << 7) + j];
        }
        // gates + cell update
        ushort hb[4];
#pragma unroll
        for (int r = 0; r < 4; ++r) {
            float iv = fsigmoid(acc[0][r]);
            float fv = fsigmoid(acc[1][r]);
            float gv = ftanh(acc[2][r]);
            float ov = fsigmoid(acc[3][r]);
            creg[r] = fv * creg[r] + iv * gv;
            float hv = ov * ftanh(creg[r]);
            hb[r] = (ushort)f2bf(hv);
        }
        const int nxt = cur ^ 1;
#pragma unroll
        for (int r = 0; r < 4; ++r) {
            h_lds[nxt][(mb + r) * 136 + j] = hb[r];
            hfb[((size_t)(b0 + mb + r) * TT + tt_c) * 256 + (dir << 7) + j] = hb[r];
        }
        // drain only LDS (h writes), NOT vmem: prefetch loads stay in flight
        asm volatile("s_waitcnt lgkmcnt(0)" ::: "memory");
        __builtin_amdgcn_s_barrier();
        __builtin_amdgcn_sched_barrier(0);
        cur = nxt;
    };

    for (int t = 0; t < TT; t += 2) {
        step(t, xrA);
        step(t + 1, xrB);
    }
}

// ---------------- logits = feat @ cls_w^T + cls_b ----------------
__global__ __launch_bounds__(256) void logits_kernel(
    const float* __restrict__ feat, const float* __restrict__ cw,
    const float* __restrict__ cb, float* __restrict__ lg)
{
    __shared__ float wls[NK*256];
    for (int i = threadIdx.x; i < NK*256; i += 256) wls[i] = cw[i];
    __syncthreads();
    size_t row = (size_t)blockIdx.x*256 + threadIdx.x;
    const float* fr = &feat[row*256];
    float acc[NK];
#pragma unroll
    for (int k = 0; k < NK; ++k) acc[k] = 0.f;
    for (int c = 0; c < 256; c += 4) {
        float4 v = *reinterpret_cast<const float4*>(&fr[c]);
#pragma unroll
        for (int k = 0; k < NK; ++k)
            acc[k] += v.x*wls[k*256 + c] + v.y*wls[k*256 + c + 1]
                    + v.z*wls[k*256 + c + 2] + v.w*wls[k*256 + c + 3];
    }
#pragma unroll
    for (int k = 0; k < NK; ++k) lg[row*NK + k] = acc[k] + cb[k];
}

// ---------------- weighted CE ----------------
__global__ __launch_bounds__(256) void ce_kernel(
    const float* __restrict__ lg, const int* __restrict__ labels,
    const float* __restrict__ cw, float* __restrict__ acc2)
{
    size_t i = (size_t)blockIdx.x*256 + threadIdx.x;
    const float* l = &lg[i*NK];
    float mx = -1e30f;
#pragma unroll
    for (int k = 0; k < NK; ++k) mx = fmaxf(mx, l[k]);
    float se = 0.f;
#pragma unroll
    for (int k = 0; k < NK; ++k) se += expf(l[k] - mx);
    float lz = mx + logf(se);
    int y = labels[i];
    bool valid = (y != -100);
    int yi = valid ? y : 0;
    float nll = lz - l[yi];
    float wv = valid ? cw[yi] : 0.f;
    __shared__ float s1[256], s2[256];
    s1[threadIdx.x] = wv*nll;
    s2[threadIdx.x] = wv;
    __syncthreads();
    for (int s = 128; s > 0; s >>= 1) {
        if (threadIdx.x < s) { s1[threadIdx.x] += s1[threadIdx.x + s]; s2[threadIdx.x] += s2[threadIdx.x + s]; }
        __syncthreads();
    }
    if (threadIdx.x == 0) { atomicAdd(&acc2[0], s1[0]); atomicAdd(&acc2[1], s2[0]); }
}

// ---------------- CRF ----------------
__global__ __launch_bounds__(64) void crf_kernel(
    const float* __restrict__ lg, const int* __restrict__ att,
    const int* __restrict__ labels, const float* __restrict__ startv,
    const float* __restrict__ trans, const float* __restrict__ endv,
    float* __restrict__ numo, float* __restrict__ logzo)
{
    int b = blockIdx.x;
    int lane = threadIdx.x;
    int lane_c = (lane < NK) ? lane : 0;
    const float* em = &lg[(size_t)b*TT*NK];
    float tr[NK];
#pragma unroll
    for (int i = 0; i < NK; ++i) tr[i] = trans[i*NK + lane_c];
    float score = startv[lane_c] + em[lane_c];

    for (int t = 1; t < TT; ++t) {
        int lt = labels[b*TT + t];
        bool m = (att[b*TT + t] != 0) && (lt != -100);
        float vals[NK];
#pragma unroll
        for (int i = 0; i < NK; ++i)
            vals[i] = __shfl(score, i, 64) + tr[i];
        if (m) {
            float mx = vals[0];
#pragma unroll
            for (int i = 1; i < NK; ++i) mx = fmaxf(mx, vals[i]);
            float sm = 0.f;
#pragma unroll
            for (int i = 0; i < NK; ++i) sm += expf(vals[i] - mx);
            score = mx + logf(sm) + em[t*NK + lane_c];
        }
    }
    float fin = (lane < NK) ? (score + endv[lane_c]) : -1e30f;
    float mx = -1e30f;
#pragma unroll
    for (int i = 0; i < NK; ++i) mx = fmaxf(mx, __shfl(fin, i, 64));
    float sm = 0.f;
#pragma unroll
    for (int i = 0; i < NK; ++i) sm += expf(__shfl(fin, i, 64) - mx);
    if (lane == 0) logzo[b] = mx + logf(sm);

    if (lane == 0) {
        int l0 = labels[b*TT];
        int tag0 = (l0 == -100) ? 0 : l0;
        bool m0 = (att[b*TT] != 0) && (l0 != -100);
        float num = startv[tag0] + em[tag0];
        int prev = tag0;
        int cnt = m0 ? 1 : 0;
        for (int t = 1; t < TT; ++t) {
            int lt = labels[b*TT + t];
            bool m = (att[b*TT + t] != 0) && (lt != -100);
            int tag = (lt == -100) ? 0 : lt;
            if (m) { num += trans[prev*NK + tag] + em[t*NK + tag]; cnt++; }
            prev = tag;
        }
        int le = cnt - 1; if (le < 0) le = 0; if (le >= TT) le = TT - 1;
        int ll = labels[b*TT + le];
        int ltag = (ll == -100) ? 0 : ll;
        num += endv[ltag];
        numo[b] = num;
    }
}

__global__ __launch_bounds__(256) void finalize_kernel(
    const float* __restrict__ numo, const float* __restrict__ logzo,
    const float* __restrict__ acc2, float* __restrict__ out)
{
    __shared__ float red[256];
    int tid = threadIdx.x;
    red[tid] = numo[tid] - logzo[tid];
    __syncthreads();
    for (int s = 128; s > 0; s >>= 1) {
        if (tid < s) red[tid] += red[tid + s];
        __syncthreads();
    }
    if (tid == 0) {
        float crf = -(red[0] / (float)BB);
        float ce = acc2[0] / acc2[1];
        out[0] = 0.8f*crf + 0.2f*ce;
    }
}

extern "C" void kernel_launch(void* const* d_in, const int* in_sizes, int n_in,
                              void* d_out, int out_size, void* d_ws, size_t ws_size,
                              hipStream_t stream)
{
    const float* emb   = (const float*)d_in[0];
    const int*   att   = (const int*)  d_in[1];
    const int*   lab   = (const int*)  d_in[2];
    const float* c5w   = (const float*)d_in[3];
    const float* c5b   = (const float*)d_in[4];
    const float* bn1g  = (const float*)d_in[5];
    const float* bn1b  = (const float*)d_in[6];
    const float* Wihf  = (const float*)d_in[7];
    const float* Whhf  = (const float*)d_in[8];
    const float* bihf  = (const float*)d_in[9];
    const float* bhhf  = (const float*)d_in[10];
    const float* Wihb  = (const float*)d_in[11];
    const float* Whhb  = (const float*)d_in[12];
    const float* bihb  = (const float*)d_in[13];
    const float* bhhb  = (const float*)d_in[14];
    const float* c7w   = (const float*)d_in[15];
    const float* c7b   = (const float*)d_in[16];
    const float* c9w   = (const float*)d_in[17];
    const float* c9b   = (const float*)d_in[18];
    const float* bn2g  = (const float*)d_in[19];
    const float* bn2b  = (const float*)d_in[20];
    const float* clsw  = (const float*)d_in[21];
    const float* clsb  = (const float*)d_in[22];
    const float* cstart= (const float*)d_in[23];
    const float* ctrans= (const float*)d_in[24];
    const float* cend  = (const float*)d_in[25];
    const float* cwts  = (const float*)d_in[26];
    (void)in_sizes; (void)n_in; (void)out_size; (void)ws_size;

    char* wsb = (char*)d_ws;
    size_t off = 0;
    auto alloc = [&](size_t bytes) { void* p = wsb + off; off += (bytes + 255) & ~(size_t)255; return p; };
    float*  y1      = (float*) alloc((size_t)4194304*4);   // (B*T,128) f32
    ushort* xg      = (ushort*)alloc((size_t)2*16777216*2);// [dir][T][B][512] bf16 (transposed)
    float*  c79     = (float*) xg;                         // aliases dir-0 half (dead after lstm)
    ushort* hfb     = (ushort*)alloc((size_t)8388608*2);   // (B*T,256) bf16
    float*  lg      = (float*) alloc((size_t)294912*4);
    ushort* Wk5     = (ushort*)alloc((size_t)655360*2);
    ushort* Wk7     = (ushort*)alloc((size_t)229376*2);
    ushort* Wk9     = (ushort*)alloc((size_t)294912*2);
    ushort* Wxg     = (ushort*)alloc((size_t)131072*2);
    float*  bias_xg = (float*) alloc((size_t)1024*4);
    float*  stats   = (float*) alloc((size_t)2048*4);
    float* bn1s = stats;
    float* bn1q = stats + 128;
    float* bn2s = stats + 256;
    float* bn2q = stats + 512;
    float* acc2 = stats + 768;
    float* numo = stats + 770;
    float* logzo = numo + 256;

    hipMemsetAsync(stats, 0, 770*sizeof(float), stream);

    prep_convw_kernel<<<2560, 256, 0, stream>>>(c5w, Wk5, 1024, 5, 655360);
    prep_convw_kernel<<<896,  256, 0, stream>>>(c7w, Wk7, 256, 7, 229376);
    prep_convw_kernel<<<1152, 256, 0, stream>>>(c9w, Wk9, 256, 9, 294912);
    prep_xg_kernel<<<516, 256, 0, stream>>>(Wihf, Wihb, bihf, bhhf, bihb, bhhb, Wxg, bias_xg);

    conv_mfma_kernel<1024,5,true,false><<<dim3(256,1), 256, 0, stream>>>(emb, Wk5, c5b, y1, 128, 0);
    bn_stats_kernel<<<256, 256, 0, stream>>>(y1, 128, 128, bn1s, bn1q);
    bn_gelu_kernel<<<16384, 256, 0, stream>>>(y1, 127, bn1s, bn1q, bn1g, bn1b, 1.0f/32768.f);

    conv_mfma_kernel<128,1,true,true,true><<<dim3(256,8), 256, 0, stream>>>(y1, Wxg, bias_xg, xg, 512, (size_t)16777216);
    lstm_mfma_kernel<<<32, 512, 0, stream>>>(xg, Whhf, Whhb, hfb);

    conv_mfma_kernel<256,7,false,false><<<dim3(256,1), 256, 0, stream>>>(hfb, Wk7, c7b, c79, 256, 0);
    conv_mfma_kernel<256,9,false,false><<<dim3(256,1), 256, 0, stream>>>(hfb, Wk9, c9b, c79 + 128, 256, 0);
    bn_stats_kernel<<<256, 256, 0, stream>>>(c79, 256, 128, bn2s, bn2q);
    bn_gelu_kernel<<<32768, 256, 0, stream>>>(c79, 255, bn2s, bn2q, bn2g, bn2b, 1.0f/32768.f);

    logits_kernel<<<128, 256, 0, stream>>>(c79, clsw, clsb, lg);
    ce_kernel<<<128, 256, 0, stream>>>(lg, lab, cwts, acc2);
    crf_kernel<<<BB, 64, 0, stream>>>(lg, att, lab, cstart, ctrans, cend, numo, logzo);
    finalize_kernel<<<1, 256, 0, stream>>>(numo, logzo, acc2, (float*)d_out);
}